// Round 13
// baseline (58.632 us; speedup 1.0000x reference)
//
#include <hip/hip_runtime.h>
#include <cmath>

// SE block: windowed mean-pool -> softsign(mW1+b1) -> sigmoid(softsign(hW2+b2)) -> gate x.
// B=32, M=2048, D=512, H=64, WIN=16 (M % WIN == 0, so reference edge-pad is a no-op).
// R12 = R8's validated pipeline (raw lgkmcnt barriers + double-buffered x prefetch,
//       VGPR=116 no-spill, FETCH 67MB) at the residency R8 lacked:
//       NG=2 groups/block -> grid=1024 -> 4 blocks/CU (VGPR=116 <= 128 allows 4 waves/SIMD).
//       R8 failed only because grid=512 pinned 2 blocks/CU; R9 failed only because
//       launch_bounds(256,4) forced VGPR->64 (spill). (256,2) is the proven-safe bound.
//       R11 proved cross-block overlap is exhausted (LDS 33->12.8KB: no change) — the
//       remaining gap to the ~31us HBM floor is per-block phase serialization, which this
//       intra-block prefetch fills: next group's 32 x-loads fly under current matmuls.

constexpr int WIN = 16;
constexpr int D   = 512;
constexpr int H   = 64;
constexpr int TPB = 256;
constexpr int NW  = 2;                    // windows per group
constexpr int NG  = 2;                    // groups per block (4 windows/block)
constexpr int GSTRIDE = NW * WIN * D / 4; // group stride in float4 = 4096

// LDS-only barrier: order LDS writes->reads across the workgroup WITHOUT draining vmcnt.
__device__ __forceinline__ void bar_lds() {
    asm volatile("s_waitcnt lgkmcnt(0)" ::: "memory");
    __builtin_amdgcn_s_barrier();
    asm volatile("" ::: "memory");        // keep later LDS ops from hoisting above barrier
}

__device__ __forceinline__ void load_group(const float4* __restrict__ xg, int tid,
                                           float4 r[NW][8]) {
#pragma unroll
    for (int w = 0; w < NW; ++w)
#pragma unroll
        for (int i = 0; i < 8; ++i)
            r[w][i] = xg[w * 2048 + i * TPB + tid];
}

// Process one group of NW windows held in r[][]; prefetch the next group's x into
// rnext[][] right after B1 so the 32 loads retire under the matmul phases.
__device__ __forceinline__ void process_group(
    const float4 r[NW][8], float4 rnext[NW][8], const float4* __restrict__ xnext,
    float4* __restrict__ yg,
    const float4* __restrict__ W1f4, const float* __restrict__ b1,
    const float4* __restrict__ W2f4, const float4* __restrict__ b2f4,
    float4* __restrict__ sA, float4* __restrict__ s_g4, float* __restrict__ s_h,
    int tid)
{
    float4* s_ps = sA;   // [NW][256]      ph1 -> mm1 reads
    float4* s_hp = sA;   // [16][NW][16]   mm1 write -> ph2b read   (aliased, barrier-separated)
    float4* s_gp = sA;   // [2][NW][128]   mm2 write -> ph3b read   (aliased, barrier-separated)

    // ---- ph1: per-thread partial sums over this thread's 8 rows (col c = tid&127)
#pragma unroll
    for (int w = 0; w < NW; ++w) {
        float4 ps = r[w][0];
#pragma unroll
        for (int i = 1; i < 8; ++i) {
            ps.x += r[w][i].x; ps.y += r[w][i].y; ps.z += r[w][i].z; ps.w += r[w][i].w;
        }
        s_ps[w * TPB + tid] = ps;
    }
    bar_lds();                                  // B1

    // ---- prefetch next group's x (independent; retires under the phases below)
    if (xnext != nullptr) load_group(xnext, tid, rnext);

    // ---- mm1 (mean folded in): h_pre[j] = (1/16) sum_k (ps[k]+ps_pair[k]) W1[k][j]
    // Thread = (p = tid>>4 k-part, j4 = tid&15); k in [p*32, p*32+32).
    {
        const int p  = tid >> 4;
        const int j4 = tid & 15;
        float4 acc[NW];
#pragma unroll
        for (int w = 0; w < NW; ++w) acc[w] = make_float4(0.f, 0.f, 0.f, 0.f);
#pragma unroll 2
        for (int kk4 = 0; kk4 < 8; ++kk4) {
            const int c4 = p * 8 + kk4;
            const int k  = c4 * 4;
            const float4 w0 = W1f4[(size_t)(k + 0) * 16 + j4];
            const float4 w1 = W1f4[(size_t)(k + 1) * 16 + j4];
            const float4 w2 = W1f4[(size_t)(k + 2) * 16 + j4];
            const float4 w3 = W1f4[(size_t)(k + 3) * 16 + j4];
#pragma unroll
            for (int w = 0; w < NW; ++w) {
                const float4 a = s_ps[w * TPB + c4];
                const float4 b = s_ps[w * TPB + c4 + 128];
                const float mv0 = a.x + b.x, mv1 = a.y + b.y;
                const float mv2 = a.z + b.z, mv3 = a.w + b.w;
                acc[w].x = fmaf(mv0, w0.x, acc[w].x); acc[w].y = fmaf(mv0, w0.y, acc[w].y);
                acc[w].z = fmaf(mv0, w0.z, acc[w].z); acc[w].w = fmaf(mv0, w0.w, acc[w].w);
                acc[w].x = fmaf(mv1, w1.x, acc[w].x); acc[w].y = fmaf(mv1, w1.y, acc[w].y);
                acc[w].z = fmaf(mv1, w1.z, acc[w].z); acc[w].w = fmaf(mv1, w1.w, acc[w].w);
                acc[w].x = fmaf(mv2, w2.x, acc[w].x); acc[w].y = fmaf(mv2, w2.y, acc[w].y);
                acc[w].z = fmaf(mv2, w2.z, acc[w].z); acc[w].w = fmaf(mv2, w2.w, acc[w].w);
                acc[w].x = fmaf(mv3, w3.x, acc[w].x); acc[w].y = fmaf(mv3, w3.y, acc[w].y);
                acc[w].z = fmaf(mv3, w3.z, acc[w].z); acc[w].w = fmaf(mv3, w3.w, acc[w].w);
            }
        }
        bar_lds();                              // B2: all s_ps reads done before overwrite
        const float sc = 1.0f / 16.0f;
#pragma unroll
        for (int w = 0; w < NW; ++w) {
            float4 v = acc[w];
            v.x *= sc; v.y *= sc; v.z *= sc; v.w *= sc;
            s_hp[(p * NW + w) * 16 + j4] = v;
        }
    }
    bar_lds();                                  // B3

    // ---- ph2b: reduce 16 k-parts, +b1, softsign
    if (tid < NW * H) {
        const float* s_hpf = reinterpret_cast<const float*>(s_hp);
        const int w = tid >> 6;
        const int j = tid & 63;
        float s = b1[j];
#pragma unroll
        for (int p = 0; p < 16; ++p) s += s_hpf[(p * NW + w) * H + j];
        s_h[w * H + j] = s / (1.0f + fabsf(s));
    }
    bar_lds();                                  // B4

    // ---- mm2: g_pre[d] = sum_j h[j] W2[j][d]; thread = (q = tid>>7, d4 = tid&127)
    {
        const float4* s_h4 = reinterpret_cast<const float4*>(s_h);  // [NW][16]
        const int q  = tid >> 7;
        const int d4 = tid & 127;
        float4 acc[NW];
#pragma unroll
        for (int w = 0; w < NW; ++w) acc[w] = make_float4(0.f, 0.f, 0.f, 0.f);
#pragma unroll 2
        for (int jj4 = 0; jj4 < 8; ++jj4) {
            const int jg = q * 8 + jj4;
            const int j  = jg * 4;
            const float4 w0 = W2f4[(size_t)(j + 0) * 128 + d4];
            const float4 w1 = W2f4[(size_t)(j + 1) * 128 + d4];
            const float4 w2 = W2f4[(size_t)(j + 2) * 128 + d4];
            const float4 w3 = W2f4[(size_t)(j + 3) * 128 + d4];
#pragma unroll
            for (int w = 0; w < NW; ++w) {
                const float4 hv = s_h4[w * 16 + jg];
                acc[w].x = fmaf(hv.x, w0.x, acc[w].x); acc[w].y = fmaf(hv.x, w0.y, acc[w].y);
                acc[w].z = fmaf(hv.x, w0.z, acc[w].z); acc[w].w = fmaf(hv.x, w0.w, acc[w].w);
                acc[w].x = fmaf(hv.y, w1.x, acc[w].x); acc[w].y = fmaf(hv.y, w1.y, acc[w].y);
                acc[w].z = fmaf(hv.y, w1.z, acc[w].z); acc[w].w = fmaf(hv.y, w1.w, acc[w].w);
                acc[w].x = fmaf(hv.z, w2.x, acc[w].x); acc[w].y = fmaf(hv.z, w2.y, acc[w].y);
                acc[w].z = fmaf(hv.z, w2.z, acc[w].z); acc[w].w = fmaf(hv.z, w2.w, acc[w].w);
                acc[w].x = fmaf(hv.w, w3.x, acc[w].x); acc[w].y = fmaf(hv.w, w3.y, acc[w].y);
                acc[w].z = fmaf(hv.w, w3.z, acc[w].z); acc[w].w = fmaf(hv.w, w3.w, acc[w].w);
            }
        }
        // s_hp reads finished at B4 -> safe to overwrite region A as s_gp
#pragma unroll
        for (int w = 0; w < NW; ++w) s_gp[(q * NW + w) * 128 + d4] = acc[w];
    }
    bar_lds();                                  // B5

    // ---- ph3b: reduce 2 j-parts, +b2, softsign, sigmoid -> s_g4
    {
        const int w  = tid >> 7;
        const int d4 = tid & 127;
        const float4 a  = s_gp[(0 * NW + w) * 128 + d4];
        const float4 b  = s_gp[(1 * NW + w) * 128 + d4];
        const float4 bb = b2f4[d4];
        float4 s;
        s.x = a.x + b.x + bb.x; s.y = a.y + b.y + bb.y;
        s.z = a.z + b.z + bb.z; s.w = a.w + b.w + bb.w;
        s.x = s.x / (1.0f + fabsf(s.x)); s.y = s.y / (1.0f + fabsf(s.y));
        s.z = s.z / (1.0f + fabsf(s.z)); s.w = s.w / (1.0f + fabsf(s.w));
        float4 g;
        g.x = 1.0f / (1.0f + __expf(-s.x)); g.y = 1.0f / (1.0f + __expf(-s.y));
        g.z = 1.0f / (1.0f + __expf(-s.z)); g.w = 1.0f / (1.0f + __expf(-s.w));
        s_g4[w * 128 + d4] = g;
    }
    bar_lds();                                  // B6

    // ---- ph4: gate from registers, store. (next group's B1 orders s_g4 vs next writes)
    {
        const int c = tid & 127;
#pragma unroll
        for (int w = 0; w < NW; ++w) {
            const float4 g = s_g4[w * 128 + c];
#pragma unroll
            for (int i = 0; i < 8; ++i) {
                float4 o;
                o.x = r[w][i].x * g.x; o.y = r[w][i].y * g.y;
                o.z = r[w][i].z * g.z; o.w = r[w][i].w * g.w;
                yg[w * 2048 + i * TPB + tid] = o;
            }
        }
    }
}

__global__ __launch_bounds__(TPB, 2) void se_pipe_kernel(
    const float* __restrict__ x,
    const float* __restrict__ W1,
    const float* __restrict__ b1,
    const float* __restrict__ W2,
    const float* __restrict__ b2,
    float* __restrict__ y)
{
    const int tid = threadIdx.x;
    const size_t base = (size_t)blockIdx.x * (size_t)(NG * NW * WIN * D);
    const float4* __restrict__ xw = reinterpret_cast<const float4*>(x + base);
    float4*       __restrict__ yw = reinterpret_cast<float4*>(y + base);

    const float4* __restrict__ W1f4 = reinterpret_cast<const float4*>(W1); // [512] x 16 f4
    const float4* __restrict__ W2f4 = reinterpret_cast<const float4*>(W2); // [64] x 128 f4
    const float4* __restrict__ b2f4 = reinterpret_cast<const float4*>(b2);

    __shared__ __align__(16) float4 sA[NW * TPB];     // 8 KB (s_ps | s_hp | s_gp)
    __shared__ __align__(16) float4 s_g4[NW * 128];   // 4 KB
    __shared__ float s_h[NW * H];                     // 512 B

    float4 rA[NW][8], rB[NW][8];

    load_group(xw, tid, rA);
    process_group(rA, rB, xw + 1 * GSTRIDE, yw,
                  W1f4, b1, W2f4, b2f4, sA, s_g4, s_h, tid);
    process_group(rB, rA, nullptr, yw + 1 * GSTRIDE,
                  W1f4, b1, W2f4, b2f4, sA, s_g4, s_h, tid);
}

extern "C" void kernel_launch(void* const* d_in, const int* in_sizes, int n_in,
                              void* d_out, int out_size, void* d_ws, size_t ws_size,
                              hipStream_t stream) {
    const float* x  = (const float*)d_in[0];
    const float* W1 = (const float*)d_in[1];
    const float* b1 = (const float*)d_in[2];
    const float* W2 = (const float*)d_in[3];
    const float* b2 = (const float*)d_in[4];
    float* y = (float*)d_out;

    const int n_windows = in_sizes[0] / (WIN * D);    // 4096
    const int n_blocks  = n_windows / (NG * NW);      // 1024 -> 4 blocks/CU
    se_pipe_kernel<<<dim3(n_blocks), dim3(TPB), 0, stream>>>(x, W1, b1, W2, b2, y);
}